// Round 1
// baseline (439.702 us; speedup 1.0000x reference)
//
#include <hip/hip_runtime.h>

#define DEVFN __device__ __forceinline__

DEVFN float sigmoidf_(float x) { return 1.f / (1.f + __expf(-x)); }

// ---------------- weight transpose: wT[(ic*9+j)*196 + oc] = w[(oc*98+ic)*9 + j]
__global__ void wtrans_kernel(const float* __restrict__ w, float* __restrict__ wT) {
    int i = blockIdx.x * 256 + threadIdx.x;
    const int n = 98 * 9 * 196;
    if (i >= n) return;
    int ic  = i / (9 * 196);
    int rem = i - ic * (9 * 196);
    int j   = rem / 196;
    int oc  = rem - j * 196;
    wT[i] = w[(oc * 98 + ic) * 9 + j];
}

// ---------------- correlation base sums ----------------
// acc_out[b][dyi*NOFF+dxi][y*W+x] += sum_{c in chunk} f1[b,c,y,x] * f2[b,c,y+dyi-OFS,x+dxi-OFS]
// (f2 zero-padded). Offsets dyi-OFS in [-OFS, NOFF-OFS).
template<int C, int CHUNK, int H, int W, int TW, int TH, int NOFF, int OFS>
__global__ void corr_kernel(const float* __restrict__ f1, const float* __restrict__ f2,
                            float* __restrict__ accout) {
    const int HW = H * W;
    const int FW = TW + NOFF - 1;
    const int FH = TH + NOFF - 1;
    __shared__ float f2s[FH * FW];
    const int y0    = blockIdx.x * TH;
    const int b     = blockIdx.y;
    const int chunk = blockIdx.z;
    const int t  = threadIdx.x;
    const int tx = t % TW;
    const int ty = t / TW;

    float acc[NOFF][NOFF];
#pragma unroll
    for (int i = 0; i < NOFF; ++i)
#pragma unroll
        for (int jj = 0; jj < NOFF; ++jj) acc[i][jj] = 0.f;

    const float* f1b = f1 + ((size_t)b * C + (size_t)chunk * CHUNK) * HW;
    const float* f2b = f2 + ((size_t)b * C + (size_t)chunk * CHUNK) * HW;
    const int myoff = (y0 + ty) * W + tx;

#pragma unroll 1
    for (int c = 0; c < CHUNK; ++c) {
        __syncthreads();
        for (int e = t; e < FH * FW; e += TW * TH) {
            int r  = e / FW, cc = e - r * FW;
            int gy = y0 - OFS + r;
            int gx = cc - OFS;
            float v = 0.f;
            if (gy >= 0 && gy < H && gx >= 0 && gx < W) v = f2b[(size_t)c * HW + gy * W + gx];
            f2s[e] = v;
        }
        __syncthreads();
        float f1v = f1b[(size_t)c * HW + myoff];
#pragma unroll
        for (int dyi = 0; dyi < NOFF; ++dyi)
#pragma unroll
            for (int dxi = 0; dxi < NOFF; ++dxi)
                acc[dyi][dxi] = fmaf(f1v, f2s[(ty + dyi) * FW + tx + dxi], acc[dyi][dxi]);
    }

    float* ao = accout + ((size_t)b * NOFF * NOFF) * HW + myoff;
#pragma unroll
    for (int dyi = 0; dyi < NOFF; ++dyi)
#pragma unroll
        for (int dxi = 0; dxi < NOFF; ++dxi)
            atomicAdd(&ao[(size_t)(dyi * NOFF + dxi) * HW], acc[dyi][dxi]);
}

// ---------------- conv3x3 (implicit GEMM, fp32) ----------------
// Input channels: ic<49 -> corr-derived (mask + leaky from acc_corr); ic>=49 -> h_pre[ic-49].
// Output tile: 64 oc x (TH x 8) px per block. Thread: 4 oc x PXC px.
template<int H, int W, int TH, int PXC, int SCALE, int SHIFT, int NOFF, int OFS, int SPLIT>
__global__ void conv_kernel(const float* __restrict__ corr_acc, const float* __restrict__ h_pre,
                            const float* __restrict__ wT, const float* __restrict__ bias,
                            float* __restrict__ Y) {
    const int HW = H * W;
    const int XH = TH + 2, XW = 8 + 2;
    __shared__ __align__(16) float Ws[9 * 64];
    __shared__ float Xs[XH * XW];

    const int tilesx = W / 8;
    const int ty0    = (blockIdx.x / tilesx) * TH;
    const int tx0    = (blockIdx.x % tilesx) * 8;
    const int ocbase = blockIdx.y * 64;
    const int b      = blockIdx.z & 1;   // B=2
    const int s      = blockIdx.z >> 1;
    const int ICPS   = 98 / SPLIT;
    const int ic0    = s * ICPS;

    const int t    = threadIdx.x;
    const int oc_g = t >> 4;             // 0..15
    const int px_g = t & 15;
    const int GPR  = 8 / PXC;            // col groups per row
    const int row  = px_g / GPR;         // 0..TH-1
    const int col0 = (px_g - row * GPR) * PXC;
    const int myoc = ocbase + oc_g * 4;

    float acc[4][PXC];
#pragma unroll
    for (int o = 0; o < 4; ++o) {
        float bv = (s == 0 && myoc + o < 196) ? bias[myoc + o] : 0.f;
#pragma unroll
        for (int c2 = 0; c2 < PXC; ++c2) acc[o][c2] = bv;
    }

#pragma unroll 1
    for (int ici = 0; ici < ICPS; ++ici) {
        const int ic = ic0 + ici;
        __syncthreads();   // previous tile fully consumed
        // ---- stage input halo tile (one channel) ----
        if (t < XH * XW) {
            int lr = t / XW, lc = t - lr * XW;
            int gy = ty0 + lr - 1, gx = tx0 + lc - 1;
            float v = 0.f;
            if (gy >= 0 && gy < H && gx >= 0 && gx < W) {
                if (ic < 49) {
                    int pi = ic / 7, pj = ic - pi * 7;
                    int dy = pi - 3, dx = pj - 3;
                    int uy = SCALE * gy + dy, ux = SCALE * gx + dx;
                    if (uy >= 0 && uy < SCALE * H && ux >= 0 && ux < SCALE * W) {
                        int idy = (dy >> SHIFT) + OFS;
                        int idx = (dx >> SHIFT) + OFS;
                        float cv = corr_acc[((size_t)b * NOFF * NOFF + idy * NOFF + idx) * HW + gy * W + gx];
                        v = cv >= 0.f ? cv : 0.01f * cv;   // leaky ReLU (masked entries are 0)
                    }
                } else {
                    v = h_pre[((size_t)b * 49 + (ic - 49)) * HW + gy * W + gx];
                }
            }
            Xs[t] = v;
        }
        // ---- stage weights: 9 x 64 oc (contiguous oc from transposed layout) ----
#pragma unroll
        for (int e = 0; e < 3; ++e) {
            int i2 = e * 256 + t;
            if (i2 < 576) {
                int j = i2 >> 6, o = i2 & 63;
                int oc = ocbase + o;
                Ws[i2] = (oc < 196) ? wT[(size_t)(ic * 9 + j) * 196 + oc] : 0.f;
            }
        }
        __syncthreads();
        // ---- preload thread's X footprint: 3 rows x (PXC+2) cols ----
        float xr[3][PXC + 2];
#pragma unroll
        for (int r2 = 0; r2 < 3; ++r2)
#pragma unroll
            for (int cc = 0; cc < PXC + 2; ++cc)
                xr[r2][cc] = Xs[(row + r2) * XW + col0 + cc];
        // ---- 3x3 x 4oc x PXC FMAs ----
#pragma unroll
        for (int j = 0; j < 9; ++j) {
            const int ky = j / 3, kx = j - ky * 3;
            float4 wv = *(const float4*)&Ws[j * 64 + oc_g * 4];
#pragma unroll
            for (int c2 = 0; c2 < PXC; ++c2) {
                float xv = xr[ky][kx + c2];
                acc[0][c2] = fmaf(wv.x, xv, acc[0][c2]);
                acc[1][c2] = fmaf(wv.y, xv, acc[1][c2]);
                acc[2][c2] = fmaf(wv.z, xv, acc[2][c2]);
                acc[3][c2] = fmaf(wv.w, xv, acc[3][c2]);
            }
        }
    }

    // ---- write partial/full conv output ----
    float* Yo = Y + ((size_t)(s * 2 + b) * 196) * HW;
#pragma unroll
    for (int o = 0; o < 4; ++o) {
        int oc = myoc + o;
        if (oc < 196) {
#pragma unroll
            for (int c2 = 0; c2 < PXC; ++c2)
                Yo[(size_t)oc * HW + (ty0 + row) * W + tx0 + col0 + c2] = acc[o][c2];
        }
    }
}

// ---------------- LSTM gates (elementwise) ----------------
template<int S>
__global__ void lstm_kernel(const float* __restrict__ Y, const float* __restrict__ c_pre,
                            float* __restrict__ h_out, float* __restrict__ c_out, int HW) {
    int i = blockIdx.x * 256 + threadIdx.x;
    int n = 2 * 49 * HW;
    if (i >= n) return;
    int b   = i / (49 * HW);
    int rem = i - b * (49 * HW);   // k*HW + p
    float g4[4];
#pragma unroll
    for (int gi = 0; gi < 4; ++gi) {
        float v = 0.f;
#pragma unroll
        for (int ss = 0; ss < S; ++ss)
            v += Y[((size_t)((ss * 2 + b) * 196) + gi * 49) * HW + rem];
        g4[gi] = v;
    }
    float iv = sigmoidf_(g4[0]);
    float fv = sigmoidf_(g4[1]);
    float ov = sigmoidf_(g4[2]);
    float gv = tanhf(g4[3]);
    float cp = c_pre[i];
    float cn = fv * cp + iv * gv;
    h_out[i] = ov * tanhf(cn);
    c_out[i] = cn;
}

extern "C" void kernel_launch(void* const* d_in, const int* in_sizes, int n_in,
                              void* d_out, int out_size, void* d_ws, size_t ws_size,
                              hipStream_t stream) {
    (void)in_sizes; (void)n_in; (void)out_size; (void)ws_size;
    const float* x0  = (const float*)d_in[0];
    const float* x1  = (const float*)d_in[1];
    const float* xp0 = (const float*)d_in[2];
    const float* xp1 = (const float*)d_in[3];
    const float* h0  = (const float*)d_in[4];
    const float* c0  = (const float*)d_in[5];
    const float* h1  = (const float*)d_in[6];
    const float* c1  = (const float*)d_in[7];
    const float* w0  = (const float*)d_in[8];
    const float* b0  = (const float*)d_in[9];
    const float* w1  = (const float*)d_in[10];
    const float* b1  = (const float*)d_in[11];
    float* out = (float*)d_out;

    float* ws    = (float*)d_ws;
    float* wT0   = ws;                     // 172872
    float* wT1   = wT0 + 172872;           // 172872
    float* accC0 = wT1 + 172872;           // 2*16*4096 = 131072
    float* accC1 = accC0 + 131072;         // 2*4*1024  = 8192
    float* Y0    = accC1 + 8192;           // 2*196*4096 = 1605632
    float* Y1    = Y0 + 1605632;           // 2*2*196*1024 = 802816

    // zero the atomic accumulation buffers (contiguous)
    hipMemsetAsync(accC0, 0, (size_t)(131072 + 8192) * sizeof(float), stream);

    wtrans_kernel<<<676, 256, 0, stream>>>(w0, wT0);
    wtrans_kernel<<<676, 256, 0, stream>>>(w1, wT1);

    // level 0: C=512, 64x64, scale 2, offsets {-2..1} (4x4)
    corr_kernel<512, 32, 64, 64, 64, 4, 4, 2><<<dim3(16, 2, 16), 256, 0, stream>>>(x0, xp0, accC0);
    // level 1: C=1024, 32x32, scale 4, offsets {-1,0} (2x2)
    corr_kernel<1024, 64, 32, 32, 32, 8, 2, 1><<<dim3(4, 2, 16), 256, 0, stream>>>(x1, xp1, accC1);

    // conv level 0: H=W=64, tile 8x8 px, 4 px/thread, no K-split
    conv_kernel<64, 64, 8, 4, 2, 1, 4, 2, 1><<<dim3(64, 4, 2), 256, 0, stream>>>(accC0, h0, wT0, b0, Y0);
    // conv level 1: H=W=32, tile 4x8 px, 2 px/thread, K-split 2
    conv_kernel<32, 32, 4, 2, 4, 2, 2, 1, 2><<<dim3(32, 4, 4), 256, 0, stream>>>(accC1, h1, wT1, b1, Y1);

    lstm_kernel<1><<<1568, 256, 0, stream>>>(Y0, c0, out + 0,      out + 401408, 4096);
    lstm_kernel<2><<<392, 256, 0, stream>>>(Y1, c1, out + 802816, out + 903168, 1024);
}

// Round 2
// 230.129 us; speedup vs baseline: 1.9107x; 1.9107x over previous
//
#include <hip/hip_runtime.h>

#define DEVFN __device__ __forceinline__

typedef __attribute__((ext_vector_type(8))) __bf16 bf16x8;
typedef __attribute__((ext_vector_type(16))) float f32x16;
typedef unsigned short ushort;

DEVFN float sigmoidf_(float x) { return 1.f / (1.f + __expf(-x)); }

DEVFN ushort f2bf(float f) {   // RNE float->bf16
    unsigned u = __float_as_uint(f);
    unsigned r = (u + 0x7FFF + ((u >> 16) & 1)) >> 16;
    return (ushort)r;
}

// ---------------- correlation base sums (multi-channel staged) ----------------
template<int C, int CHUNK, int CH, int H, int W, int TW, int TH, int NOFF, int OFS>
__global__ void corr_kernel(const float* __restrict__ f1, const float* __restrict__ f2,
                            float* __restrict__ accout) {
    const int HW = H * W;
    const int FW = TW + NOFF - 1;
    const int FH = TH + NOFF - 1;
    __shared__ float f2s[CH][FH * FW];
    const int y0    = blockIdx.x * TH;
    const int b     = blockIdx.y;
    const int chunk = blockIdx.z;
    const int t  = threadIdx.x;
    const int tx = t % TW;
    const int ty = t / TW;

    float acc[NOFF][NOFF];
#pragma unroll
    for (int i = 0; i < NOFF; ++i)
#pragma unroll
        for (int jj = 0; jj < NOFF; ++jj) acc[i][jj] = 0.f;

    const float* f1b = f1 + ((size_t)b * C + (size_t)chunk * CHUNK) * HW;
    const float* f2b = f2 + ((size_t)b * C + (size_t)chunk * CHUNK) * HW;
    const int myoff = (y0 + ty) * W + tx;

#pragma unroll 1
    for (int c0 = 0; c0 < CHUNK; c0 += CH) {
        __syncthreads();
        for (int e = t; e < CH * FH * FW; e += TW * TH) {
            int ch = e / (FH * FW);
            int e2 = e - ch * (FH * FW);
            int r  = e2 / FW, cc = e2 - r * FW;
            int gy = y0 - OFS + r;
            int gx = cc - OFS;
            float v = 0.f;
            if (gy >= 0 && gy < H && gx >= 0 && gx < W) v = f2b[(size_t)(c0 + ch) * HW + gy * W + gx];
            f2s[ch][e2] = v;
        }
        __syncthreads();
#pragma unroll
        for (int ch = 0; ch < CH; ++ch) {
            float f1v = f1b[(size_t)(c0 + ch) * HW + myoff];
#pragma unroll
            for (int dyi = 0; dyi < NOFF; ++dyi)
#pragma unroll
                for (int dxi = 0; dxi < NOFF; ++dxi)
                    acc[dyi][dxi] = fmaf(f1v, f2s[ch][(ty + dyi) * FW + tx + dxi], acc[dyi][dxi]);
        }
    }

    float* ao = accout + ((size_t)b * NOFF * NOFF) * HW + myoff;
#pragma unroll
    for (int dyi = 0; dyi < NOFF; ++dyi)
#pragma unroll
        for (int dxi = 0; dxi < NOFF; ++dxi)
            atomicAdd(&ao[(size_t)(dyi * NOFF + dxi) * HW], acc[dyi][dxi]);
}

// ---------------- build conv input: Xin[b][y][x][ic128] bf16 ----------------
// ic<49: corr expansion (mask+leaky), 49..97: h_pre, 98..127: 0
template<int H, int W, int SCALE, int SHIFT, int NOFF, int OFS>
__global__ void xbuild_kernel(const float* __restrict__ corr_acc, const float* __restrict__ h_pre,
                              ushort* __restrict__ Xin) {
    const int HW = H * W;
    int i = blockIdx.x * 256 + threadIdx.x;
    if (i >= 2 * HW * 16) return;
    int g  = i & 15;
    int px = (i >> 4) % HW;
    int b  = (i >> 4) / HW;
    int y = px / W, x = px - y * W;
    ushort out8[8];
#pragma unroll
    for (int j = 0; j < 8; ++j) {
        int ic = g * 8 + j;
        float v = 0.f;
        if (ic < 49) {
            int pi = ic / 7, pj = ic - pi * 7;
            int dy = pi - 3, dx = pj - 3;
            int uy = SCALE * y + dy, ux = SCALE * x + dx;
            if (uy >= 0 && uy < SCALE * H && ux >= 0 && ux < SCALE * W) {
                int idy = (dy >> SHIFT) + OFS;
                int idx = (dx >> SHIFT) + OFS;
                float cv = corr_acc[((size_t)b * NOFF * NOFF + idy * NOFF + idx) * HW + px];
                v = cv >= 0.f ? cv : 0.01f * cv;
            }
        } else if (ic < 98) {
            v = h_pre[((size_t)b * 49 + (ic - 49)) * HW + px];
        }
        out8[j] = f2bf(v);
    }
    *reinterpret_cast<uint4*>(Xin + (size_t)i * 8) = *reinterpret_cast<uint4*>(out8);
}

// ---------------- weight prep: Wmf[tap9][icg16][oc256][8] bf16 ----------------
__global__ void wprep_kernel(const float* __restrict__ w, ushort* __restrict__ Wmf) {
    int i = blockIdx.x * 256 + threadIdx.x;
    const int n = 9 * 16 * 256 * 8;
    if (i >= n) return;
    int iEl = i & 7;
    int oc  = (i >> 3) & 255;
    int icg = (i >> 11) & 15;
    int tap = i >> 15;
    int ic  = icg * 8 + iEl;
    float v = (oc < 196 && ic < 98) ? w[((size_t)oc * 98 + ic) * 9 + tap] : 0.f;
    Wmf[i] = f2bf(v);
}

// ---------------- conv3x3 via mfma_f32_32x32x16_bf16 ----------------
// Block: 4 waves, output region 8 rows x 16 cols (128 px), 64 oc.
// Wave w: px rows 2w..2w+1, cols 0..15 (one 32-px N-tile); 2 oc M-tiles.
// A (M=oc x K=ic) = weights in registers; B (K x N=px) = X from LDS halo.
template<int H, int W, int SPLIT, int ICPS, int NKC, int STRIDE>
__global__ void convmf_kernel(const ushort* __restrict__ Xin, const ushort* __restrict__ Wmf,
                              float* __restrict__ Y) {
    const int HW = H * W;
    __shared__ ushort Xs[180 * STRIDE];
    const int tilesx = W / 16;
    const int by0 = (blockIdx.x / tilesx) * 8;
    const int bx0 = (blockIdx.x % tilesx) * 16;
    const int ocb = blockIdx.y * 64;
    const int b   = blockIdx.z & 1;
    const int s   = blockIdx.z >> 1;
    const int t   = threadIdx.x;
    const int wv  = t >> 6;
    const int l   = t & 63;
    const int G   = ICPS / 8;

    // ---- stage halo (10x18 px) x ICPS ic, bf16, ic-contiguous ----
    for (int u = t; u < 180 * G; u += 256) {
        int px = u / G, g = u - px * G;
        int gy = by0 + px / 18 - 1;
        int gx = bx0 + px % 18 - 1;
        uint4 v = make_uint4(0u, 0u, 0u, 0u);
        if (gy >= 0 && gy < H && gx >= 0 && gx < W)
            v = *reinterpret_cast<const uint4*>(Xin + (((size_t)b * HW + gy * W + gx) * 128 + s * ICPS + g * 8));
        *reinterpret_cast<uint4*>(&Xs[px * STRIDE + g * 8]) = v;
    }
    __syncthreads();

    f32x16 acc0 = {};
    f32x16 acc1 = {};
    const int n    = l & 31;      // A row (oc), B col (px), D col
    const int hi   = l >> 5;      // k-group
    const int wrow = 2 * wv + (n >> 4);
    const int wcol = n & 15;

#pragma unroll 1
    for (int kc = 0; kc < NKC; ++kc) {
        // ---- load A fragments: 2 oc-tiles x 9 taps (global, L2-resident) ----
        bf16x8 af[2][9];
        const int icg = (s * ICPS + kc * 16) / 8 + hi;
        const ushort* wp = Wmf + ((size_t)icg * 256 + ocb + n) * 8;
#pragma unroll
        for (int j = 0; j < 9; ++j) {
            af[0][j] = *reinterpret_cast<const bf16x8*>(wp + (size_t)j * 16 * 256 * 8);
            af[1][j] = *reinterpret_cast<const bf16x8*>(wp + (size_t)j * 16 * 256 * 8 + 32 * 8);
        }
#pragma unroll
        for (int j = 0; j < 9; ++j) {
            const int ky = j / 3, kx = j - (j / 3) * 3;
            const int hp = (wrow + ky) * 18 + wcol + kx;
            bf16x8 bf = *reinterpret_cast<const bf16x8*>(&Xs[hp * STRIDE + kc * 16 + hi * 8]);
            acc0 = __builtin_amdgcn_mfma_f32_32x32x16_bf16(af[0][j], bf, acc0, 0, 0, 0);
            acc1 = __builtin_amdgcn_mfma_f32_32x32x16_bf16(af[1][j], bf, acc1, 0, 0, 0);
        }
    }

    // ---- writeout: D col = px (coalesced across lanes), row = oc ----
    float* Yo = Y + ((size_t)(s * 2 + b) * 196) * HW;
    const int po = (by0 + wrow) * W + bx0 + wcol;
#pragma unroll
    for (int r = 0; r < 16; ++r) {
        int m = (r & 3) + 8 * (r >> 2) + 4 * hi;
        int oc0 = ocb + m;
        if (oc0 < 196) Yo[(size_t)oc0 * HW + po] = acc0[r];
        int oc1 = ocb + 32 + m;
        if (oc1 < 196) Yo[(size_t)oc1 * HW + po] = acc1[r];
    }
}

// ---------------- LSTM gates (split-reduce + bias + elementwise) ----------------
template<int S, int HW>
__global__ void lstm_kernel(const float* __restrict__ Y, const float* __restrict__ bias,
                            const float* __restrict__ c_pre,
                            float* __restrict__ h_out, float* __restrict__ c_out) {
    int i = blockIdx.x * 256 + threadIdx.x;
    const int n = 2 * 49 * HW;
    if (i >= n) return;
    int b   = i / (49 * HW);
    int rem = i - b * (49 * HW);   // k*HW + p
    int k   = rem / HW;
    float g4[4];
#pragma unroll
    for (int gi = 0; gi < 4; ++gi) {
        float v = bias[gi * 49 + k];
#pragma unroll
        for (int ss = 0; ss < S; ++ss)
            v += Y[((size_t)((ss * 2 + b) * 196) + gi * 49) * HW + rem];
        g4[gi] = v;
    }
    float iv = sigmoidf_(g4[0]);
    float fv = sigmoidf_(g4[1]);
    float ov = sigmoidf_(g4[2]);
    float gv = tanhf(g4[3]);
    float cp = c_pre[i];
    float cn = fv * cp + iv * gv;
    h_out[i] = ov * tanhf(cn);
    c_out[i] = cn;
}

extern "C" void kernel_launch(void* const* d_in, const int* in_sizes, int n_in,
                              void* d_out, int out_size, void* d_ws, size_t ws_size,
                              hipStream_t stream) {
    (void)in_sizes; (void)n_in; (void)out_size; (void)ws_size;
    const float* x0  = (const float*)d_in[0];
    const float* x1  = (const float*)d_in[1];
    const float* xp0 = (const float*)d_in[2];
    const float* xp1 = (const float*)d_in[3];
    const float* h0  = (const float*)d_in[4];
    const float* c0  = (const float*)d_in[5];
    const float* h1  = (const float*)d_in[6];
    const float* c1  = (const float*)d_in[7];
    const float* w0  = (const float*)d_in[8];
    const float* b0  = (const float*)d_in[9];
    const float* w1  = (const float*)d_in[10];
    const float* b1  = (const float*)d_in[11];
    float* out = (float*)d_out;

    // workspace layout (floats; all offsets 16B aligned)
    float* ws = (float*)d_ws;
    float*  Wmf0f  = ws;                       // 147456 f (294912 bf16)
    float*  Wmf1f  = Wmf0f + 147456;           // 147456 f
    float*  accC0  = Wmf1f + 147456;           // 131072 f
    float*  accC1  = accC0 + 131072;           // 8192 f
    float*  Xin0f  = accC1 + 8192;             // 524288 f (2*4096*128 bf16)
    float*  Xin1f  = Xin0f + 524288;           // 131072 f
    float*  Y0     = Xin1f + 131072;           // 2 splits * 2b * 196 * 4096 = 3211264 f
    float*  Y1     = Y0 + 3211264;             // 4 splits * 2b * 196 * 1024 = 1605632 f
    ushort* Wmf0 = (ushort*)Wmf0f;
    ushort* Wmf1 = (ushort*)Wmf1f;
    ushort* Xin0 = (ushort*)Xin0f;
    ushort* Xin1 = (ushort*)Xin1f;

    // zero atomic accumulation buffers (contiguous)
    hipMemsetAsync(accC0, 0, (size_t)(131072 + 8192) * sizeof(float), stream);

    wprep_kernel<<<1152, 256, 0, stream>>>(w0, Wmf0);
    wprep_kernel<<<1152, 256, 0, stream>>>(w1, Wmf1);

    // level 0: C=512, 64x64, scale 2, offsets {-2..1} (4x4), 8 ch/round
    corr_kernel<512, 32, 8, 64, 64, 64, 4, 4, 2><<<dim3(16, 2, 16), 256, 0, stream>>>(x0, xp0, accC0);
    // level 1: C=1024, 32x32, scale 4, offsets {-1,0} (2x2), 16 ch/round
    corr_kernel<1024, 64, 16, 32, 32, 32, 8, 2, 1><<<dim3(4, 2, 16), 256, 0, stream>>>(x1, xp1, accC1);

    xbuild_kernel<64, 64, 2, 1, 4, 2><<<512, 256, 0, stream>>>(accC0, h0, Xin0);
    xbuild_kernel<32, 32, 4, 2, 2, 1><<<128, 256, 0, stream>>>(accC1, h1, Xin1);

    // conv level 0: split 2 (64 ic each, 4 kc-chunks), LDS stride 72
    convmf_kernel<64, 64, 2, 64, 4, 72><<<dim3(32, 4, 4), 256, 0, stream>>>(Xin0, Wmf0, Y0);
    // conv level 1: split 4 (32 ic each, 2 kc-chunks), LDS stride 40
    convmf_kernel<32, 32, 4, 32, 2, 40><<<dim3(8, 4, 8), 256, 0, stream>>>(Xin1, Wmf1, Y1);

    lstm_kernel<2, 4096><<<1568, 256, 0, stream>>>(Y0, b0, c0, out + 0,      out + 401408);
    lstm_kernel<4, 1024><<<392,  256, 0, stream>>>(Y1, b1, c1, out + 802816, out + 903168);
}